// Round 8
// baseline (535.115 us; speedup 1.0000x reference)
//
#include <hip/hip_runtime.h>

typedef short s16x8 __attribute__((ext_vector_type(8)));   // 8 bf16 = 4 VGPRs
typedef float fx4 __attribute__((ext_vector_type(4)));     // MFMA acc

#define AS_G(p) ((const __attribute__((address_space(1))) void*)(p))
#define AS_L(p) ((__attribute__((address_space(3))) void*)(p))

__device__ inline unsigned short f32_to_bf16(float f) {
    unsigned int u = __float_as_uint(f);
    return (unsigned short)((u + 0x7fffu + ((u >> 16) & 1u)) >> 16);
}
__device__ inline float bf16_to_f32(unsigned short b) {
    return __uint_as_float(((unsigned int)b) << 16);
}
__device__ inline void split2(float a, unsigned short& hi, unsigned short& lo) {
    hi = f32_to_bf16(a);
    lo = f32_to_bf16(a - bf16_to_f32(hi));
}

// ===================== graph preprocessing =====================

__global__ void k_deg(const int* __restrict__ dst, int E, int* __restrict__ deg) {
    int i = blockIdx.x * blockDim.x + threadIdx.x;
    if (i < E) atomicAdd(&deg[dst[i]], 1);
}

__global__ void k_dinv(const int* __restrict__ deg, int N, float* __restrict__ dinv) {
    int i = blockIdx.x * blockDim.x + threadIdx.x;
    if (i < N) dinv[i] = 1.0f / sqrtf((float)(deg[i] + 1));
}

__global__ void k_scan1(const int* __restrict__ deg, int N, int* __restrict__ part, int* __restrict__ bsum) {
    __shared__ int s[256];
    int i = blockIdx.x * 256 + threadIdx.x;
    int v = (i < N) ? deg[i] : 0;
    s[threadIdx.x] = v;
    __syncthreads();
    for (int off = 1; off < 256; off <<= 1) {
        int t = (threadIdx.x >= off) ? s[threadIdx.x - off] : 0;
        __syncthreads();
        s[threadIdx.x] += t;
        __syncthreads();
    }
    if (i < N) part[i] = s[threadIdx.x] - v;
    if (threadIdx.x == 255) bsum[blockIdx.x] = s[255];
}

__global__ void k_scan2(int* __restrict__ bsum, int nb) {
    __shared__ int s[256];
    int v = (threadIdx.x < nb) ? bsum[threadIdx.x] : 0;
    s[threadIdx.x] = v;
    __syncthreads();
    for (int off = 1; off < 256; off <<= 1) {
        int t = (threadIdx.x >= off) ? s[threadIdx.x - off] : 0;
        __syncthreads();
        s[threadIdx.x] += t;
        __syncthreads();
    }
    if (threadIdx.x < nb) bsum[threadIdx.x] = s[threadIdx.x] - v;
}

__global__ void k_scan3(const int* __restrict__ part, const int* __restrict__ bsum, int N, int E,
                        int* __restrict__ rowptr, int* __restrict__ cursor) {
    int i = blockIdx.x * 256 + threadIdx.x;
    if (i < N) {
        int v = part[i] + bsum[blockIdx.x];
        rowptr[i] = v;
        cursor[i] = v;
    }
    if (i == 0) rowptr[N] = E;
}

__global__ void k_fill(const int* __restrict__ src, const int* __restrict__ dst, int E,
                       const float* __restrict__ dinv, int* __restrict__ cursor,
                       int* __restrict__ col, float* __restrict__ nrm) {
    int e = blockIdx.x * blockDim.x + threadIdx.x;
    if (e < E) {
        int s = src[e], d = dst[e];
        int p = atomicAdd(&cursor[d], 1);
        col[p] = s;
        nrm[p] = dinv[s] * dinv[d];
    }
}

__global__ void k_gbounds(const int* __restrict__ batch, int N, int ngraphs, int* __restrict__ gstart) {
    int g = threadIdx.x;
    if (g > ngraphs) return;
    if (g == ngraphs) { gstart[g] = N; return; }
    int lo = 0, hi = N;
    while (lo < hi) {
        int mid = (lo + hi) >> 1;
        if (batch[mid] < g) lo = mid + 1; else hi = mid;
    }
    gstart[g] = lo;
}

// W [K][M] fp32 -> W^T split bf16 [M][K] (so B-fragments read contiguous k)
__global__ void k_split_wT(const float* __restrict__ W, int K, int M,
                           unsigned short* __restrict__ hiT, unsigned short* __restrict__ loT) {
    int i = blockIdx.x * 256 + threadIdx.x;
    if (i < K * M) {
        int k = i / M, n = i - k * M;
        unsigned short h, l;
        split2(W[i], h, l);
        hiT[(size_t)n * K + k] = h;
        loT[(size_t)n * K + k] = l;
    }
}

// ===================== split-bf16 MFMA GEMM + fused bias/ReLU =====================
// C[N x 256] = relu(A[N x K] @ B[K x 256] + bias), A split bf16, B pre-transposed split.
// C = Ahi*Bhi + Ahi*Blo + Alo*Bhi in fp32 acc (error ~2^-17 rel).
// Block 128x128, 4 waves 2x2, wave tile 64x64 = 4x4 mfma_f32_16x16x32_bf16.
// global_load_lds width=16; XOR bank-swizzle folded into per-lane global addresses.

__global__ __launch_bounds__(256) void k_gemm_mfma(
    const unsigned short* __restrict__ Ahi, const unsigned short* __restrict__ Alo,
    const unsigned short* __restrict__ BhiT, const unsigned short* __restrict__ BloT,
    const float* __restrict__ bias, float* __restrict__ C, int Nrows, int K) {
    __shared__ __align__(16) unsigned short sAhi[128 * 32];
    __shared__ __align__(16) unsigned short sAlo[128 * 32];
    __shared__ __align__(16) unsigned short sBhi[128 * 32];
    __shared__ __align__(16) unsigned short sBlo[128 * 32];

    const int tid = threadIdx.x;
    const int wid = tid >> 6, lane = tid & 63;
    const int row0 = blockIdx.y * 128;
    const int col0 = blockIdx.x * 128;
    const int wrow = wid & 1, wcol = wid >> 1;
    const int quad = lane >> 4, l16 = lane & 15;

    const unsigned short* garr = (wid == 0) ? Ahi : (wid == 1) ? Alo : (wid == 2) ? BhiT : BloT;
    unsigned short* sarr = (wid == 0) ? sAhi : (wid == 1) ? sAlo : (wid == 2) ? sBhi : sBlo;
    const bool isA = (wid < 2);

    const unsigned short* gp[8];
#pragma unroll
    for (int i = 0; i < 8; ++i) {
        int r = 16 * i + (lane >> 2);            // local row within 128-tile
        int s = lane & 3;                        // physical 16B slot in row
        int q = (s - (r >> 1)) & 3;              // logical k-chunk stored at this slot
        int grow = isA ? min(row0 + r, Nrows - 1) : (col0 + r);
        gp[i] = garr + (size_t)grow * K + q * 8;
    }

    int aidx[4], bidx[4];
#pragma unroll
    for (int t = 0; t < 4; ++t) {
        int ra = wrow * 64 + t * 16 + l16;
        aidx[t] = ra * 32 + ((quad + (ra >> 1)) & 3) * 8;
        int rb = wcol * 64 + t * 16 + l16;
        bidx[t] = rb * 32 + ((quad + (rb >> 1)) & 3) * 8;
    }

    fx4 acc[4][4] = {};

    for (int k0 = 0; k0 < K; k0 += 32) {
#pragma unroll
        for (int i = 0; i < 8; ++i)
            __builtin_amdgcn_global_load_lds(AS_G(gp[i] + k0), AS_L((char*)sarr + i * 1024), 16, 0, 0);
        __syncthreads();

        s16x8 ah[4], al[4];
#pragma unroll
        for (int mi = 0; mi < 4; ++mi) {
            ah[mi] = *(const s16x8*)&sAhi[aidx[mi]];
            al[mi] = *(const s16x8*)&sAlo[aidx[mi]];
        }
#pragma unroll
        for (int nj = 0; nj < 4; ++nj) {
            s16x8 bh = *(const s16x8*)&sBhi[bidx[nj]];
            s16x8 bl = *(const s16x8*)&sBlo[bidx[nj]];
#pragma unroll
            for (int mi = 0; mi < 4; ++mi) {
                acc[mi][nj] = __builtin_amdgcn_mfma_f32_16x16x32_bf16(ah[mi], bh, acc[mi][nj], 0, 0, 0);
                acc[mi][nj] = __builtin_amdgcn_mfma_f32_16x16x32_bf16(ah[mi], bl, acc[mi][nj], 0, 0, 0);
                acc[mi][nj] = __builtin_amdgcn_mfma_f32_16x16x32_bf16(al[mi], bh, acc[mi][nj], 0, 0, 0);
            }
        }
        __syncthreads();
    }

    // C/D layout: col = lane&15, row = quad*4 + reg  [m89-verified]
#pragma unroll
    for (int mi = 0; mi < 4; ++mi) {
        const int rbase = row0 + wrow * 64 + mi * 16 + quad * 4;
#pragma unroll
        for (int nj = 0; nj < 4; ++nj) {
            const int c = col0 + wcol * 64 + nj * 16 + l16;
            const float bc = bias[c];
#pragma unroll
            for (int reg = 0; reg < 4; ++reg) {
                int r = rbase + reg;
                if (r < Nrows) C[(size_t)r * 256 + c] = fmaxf(acc[mi][nj][reg] + bc, 0.f);
            }
        }
    }
}

// ===================== aggregation (pure  Â·H : selfnorm + weighted neighbor sum) ======
// PERSISTENT grid-stride waves: each wave handles ~N/8192 nodes, which averages the
// Poisson-degree imbalance that capped wave-per-node occupancy at 57%.
#define AGG_BLOCKS 2048

// D=128 (layer 0 on raw x): lane owns float2; output split-bf16.
__global__ __launch_bounds__(256) void k_agg128(const float* __restrict__ X, const int* __restrict__ rowptr,
                                                const int* __restrict__ col, const float* __restrict__ nrm,
                                                const float* __restrict__ dinv,
                                                unsigned short* __restrict__ outHi,
                                                unsigned short* __restrict__ outLo, int N) {
    const int wave = threadIdx.x >> 6, lane = threadIdx.x & 63;
    const int nw = gridDim.x * 4;
    for (int v = blockIdx.x * 4 + wave; v < N; v += nw) {
        const float di = dinv[v];
        const float selfn = di * di;
        float2 h = ((const float2*)&X[(size_t)v * 128])[lane];
        float ax = selfn * h.x, ay = selfn * h.y;

        int e = rowptr[v];
        const int end = rowptr[v + 1];
        for (; e + 8 <= end; e += 8) {
            int u[8]; float w[8]; float2 g[8];
#pragma unroll
            for (int j = 0; j < 8; ++j) { u[j] = col[e + j]; w[j] = nrm[e + j]; }
#pragma unroll
            for (int j = 0; j < 8; ++j) g[j] = ((const float2*)&X[(size_t)u[j] * 128])[lane];
#pragma unroll
            for (int j = 0; j < 8; ++j) { ax += w[j] * g[j].x; ay += w[j] * g[j].y; }
        }
        for (; e < end; ++e) {
            const int u = col[e];
            const float w = nrm[e];
            float2 g = ((const float2*)&X[(size_t)u * 128])[lane];
            ax += w * g.x; ay += w * g.y;
        }

        ushort2 hi2, lo2;
        split2(ax, hi2.x, lo2.x);
        split2(ay, hi2.y, lo2.y);
        ((ushort2*)outHi)[(size_t)v * 64 + lane] = hi2;
        ((ushort2*)outLo)[(size_t)v * 64 + lane] = lo2;
    }
}

// D=256 (layers 1,2 on fp32 H): lane owns float4; output split-bf16.
__global__ __launch_bounds__(256) void k_agg256(const float* __restrict__ H, const int* __restrict__ rowptr,
                                                const int* __restrict__ col, const float* __restrict__ nrm,
                                                const float* __restrict__ dinv,
                                                unsigned short* __restrict__ outHi,
                                                unsigned short* __restrict__ outLo, int N) {
    const int wave = threadIdx.x >> 6, lane = threadIdx.x & 63;
    const int nw = gridDim.x * 4;
    for (int v = blockIdx.x * 4 + wave; v < N; v += nw) {
        const float di = dinv[v];
        const float selfn = di * di;
        float4 h = ((const float4*)&H[(size_t)v * 256])[lane];
        float ax = selfn * h.x, ay = selfn * h.y, az = selfn * h.z, aw = selfn * h.w;

        int e = rowptr[v];
        const int end = rowptr[v + 1];
        for (; e + 8 <= end; e += 8) {
            int u[8]; float w[8]; float4 g[8];
#pragma unroll
            for (int j = 0; j < 8; ++j) { u[j] = col[e + j]; w[j] = nrm[e + j]; }
#pragma unroll
            for (int j = 0; j < 8; ++j) g[j] = ((const float4*)&H[(size_t)u[j] * 256])[lane];
#pragma unroll
            for (int j = 0; j < 8; ++j) {
                ax += w[j] * g[j].x; ay += w[j] * g[j].y; az += w[j] * g[j].z; aw += w[j] * g[j].w;
            }
        }
        for (; e < end; ++e) {
            const int u = col[e];
            const float w = nrm[e];
            float4 g = ((const float4*)&H[(size_t)u * 256])[lane];
            ax += w * g.x; ay += w * g.y; az += w * g.z; aw += w * g.w;
        }

        ushort4 hi4, lo4;
        split2(ax, hi4.x, lo4.x);
        split2(ay, hi4.y, lo4.y);
        split2(az, hi4.z, lo4.z);
        split2(aw, hi4.w, lo4.w);
        ((ushort4*)outHi)[(size_t)v * 64 + lane] = hi4;
        ((ushort4*)outLo)[(size_t)v * 64 + lane] = lo4;
    }
}

// ===================== mean pool, two-stage deterministic tree =====================
#define POOL_S 32

__global__ __launch_bounds__(256) void k_pool1(const float* __restrict__ H, const int* __restrict__ gstart,
                                               float* __restrict__ partial) {
    const int gid = blockIdx.x, slice = blockIdx.y, t = threadIdx.x;
    const int start = gstart[gid], end = gstart[gid + 1];
    const int len = end - start;
    const int chunk = (len + POOL_S - 1) / POOL_S;
    int a = start + slice * chunk;
    int b = a + chunk; if (b > end) b = end;
    float acc = 0.f;
    for (int n = a; n < b; ++n) acc += H[(size_t)n * 256 + t];
    partial[((size_t)gid * POOL_S + slice) * 256 + t] = acc;
}

__global__ __launch_bounds__(256) void k_pool2(const float* __restrict__ partial, const int* __restrict__ gstart,
                                               float* __restrict__ g) {
    const int gid = blockIdx.x, t = threadIdx.x;
    float acc = 0.f;
#pragma unroll
    for (int s = 0; s < POOL_S; ++s) acc += partial[((size_t)gid * POOL_S + s) * 256 + t];
    const float c = (float)(gstart[gid + 1] - gstart[gid]);
    g[gid * 256 + t] = acc / fmaxf(c, 1.0f);
}

// ===================== classifier head =====================

__global__ __launch_bounds__(256) void k_cls(const float* __restrict__ g, const float* __restrict__ Wc1,
                                             const float* __restrict__ bc1, const float* __restrict__ Wc2,
                                             const float* __restrict__ bc2, float* __restrict__ out) {
    __shared__ float sg[256], sh[256];
    const int b = blockIdx.x, t = threadIdx.x;
    sg[t] = g[b * 256 + t];
    __syncthreads();
    float acc = bc1[t];
    for (int k = 0; k < 256; ++k) acc += sg[k] * Wc1[k * 256 + t];
    sh[t] = fmaxf(acc, 0.f);
    __syncthreads();
    if (t < 5) {
        float o = bc2[t];
        for (int k = 0; k < 256; ++k) o += sh[k] * Wc2[k * 5 + t];
        out[b * 5 + t] = o;
    }
}

// ===================== launch =====================

extern "C" void kernel_launch(void* const* d_in, const int* in_sizes, int n_in,
                              void* d_out, int out_size, void* d_ws, size_t ws_size,
                              hipStream_t stream) {
    const float* x    = (const float*)d_in[0];
    const int*   eidx = (const int*)d_in[1];
    const int*   batch= (const int*)d_in[2];
    const float* W0 = (const float*)d_in[3];  const float* b0 = (const float*)d_in[4];
    const float* W1 = (const float*)d_in[5];  const float* b1 = (const float*)d_in[6];
    const float* W2 = (const float*)d_in[7];  const float* b2 = (const float*)d_in[8];
    const float* Wc1= (const float*)d_in[9];  const float* bc1= (const float*)d_in[10];
    const float* Wc2= (const float*)d_in[11]; const float* bc2= (const float*)d_in[12];
    float* out = (float*)d_out;

    const int N   = in_sizes[2];       // 50000
    const int E   = in_sizes[1] / 2;   // 500000
    const int DIN = in_sizes[0] / N;   // 128
    const int DH  = in_sizes[4];       // 256
    const int* src = eidx;
    const int* dst = eidx + E;

    char* p = (char*)d_ws;
    auto alloc = [&](size_t bytes) {
        char* r = p;
        p += (bytes + 255) & ~(size_t)255;
        return (void*)r;
    };
    float*          hbuf = (float*)alloc((size_t)N * DH * 4);           // gemm out (fp32), agg in, pool in
    unsigned short* hhi  = (unsigned short*)alloc((size_t)N * DH * 2);  // agg split out / gemm A in
    unsigned short* hlo  = (unsigned short*)alloc((size_t)N * DH * 2);
    unsigned short* w0hi = (unsigned short*)alloc((size_t)DH * DIN * 2);
    unsigned short* w0lo = (unsigned short*)alloc((size_t)DH * DIN * 2);
    unsigned short* w1hi = (unsigned short*)alloc((size_t)DH * DH * 2);
    unsigned short* w1lo = (unsigned short*)alloc((size_t)DH * DH * 2);
    unsigned short* w2hi = (unsigned short*)alloc((size_t)DH * DH * 2);
    unsigned short* w2lo = (unsigned short*)alloc((size_t)DH * DH * 2);
    int*   deg   = (int*)alloc((size_t)N * 4);
    float* dinv  = (float*)alloc((size_t)N * 4);
    int*   part  = (int*)alloc((size_t)N * 4);
    int*   bsum  = (int*)alloc(256 * 4);
    int*   rowptr= (int*)alloc((size_t)(N + 1) * 4);
    int*   cursor= (int*)alloc((size_t)N * 4);
    int*   col   = (int*)alloc((size_t)E * 4);
    float* nrm   = (float*)alloc((size_t)E * 4);
    int*   gstart= (int*)alloc(65 * 4);
    float* ppool = (float*)alloc(64 * (size_t)POOL_S * DH * 4);
    float* gpool = (float*)alloc(64 * (size_t)DH * 4);

    hipMemsetAsync(deg, 0, (size_t)N * 4, stream);

    const int nb = (N + 255) / 256;
    k_deg <<<(E + 255) / 256, 256, 0, stream>>>(dst, E, deg);
    k_dinv<<<nb, 256, 0, stream>>>(deg, N, dinv);
    k_scan1<<<nb, 256, 0, stream>>>(deg, N, part, bsum);
    k_scan2<<<1, 256, 0, stream>>>(bsum, nb);
    k_scan3<<<nb, 256, 0, stream>>>(part, bsum, N, E, rowptr, cursor);
    k_fill<<<(E + 255) / 256, 256, 0, stream>>>(src, dst, E, dinv, cursor, col, nrm);
    k_gbounds<<<1, 128, 0, stream>>>(batch, N, 64, gstart);

    k_split_wT<<<(DIN * DH + 255) / 256, 256, 0, stream>>>(W0, DIN, DH, w0hi, w0lo);
    k_split_wT<<<(DH * DH + 255) / 256, 256, 0, stream>>>(W1, DH, DH, w1hi, w1lo);
    k_split_wT<<<(DH * DH + 255) / 256, 256, 0, stream>>>(W2, DH, DH, w2hi, w2lo);

    dim3 gemmGrid(DH / 128, (N + 127) / 128);

    // layer 0: agg(x) [128-d, half gather traffic] -> gemm(relu(.W0+b0))
    k_agg128<<<AGG_BLOCKS, 256, 0, stream>>>(x, rowptr, col, nrm, dinv, hhi, hlo, N);
    k_gemm_mfma<<<gemmGrid, 256, 0, stream>>>(hhi, hlo, w0hi, w0lo, b0, hbuf, N, DIN);
    // layer 1
    k_agg256<<<AGG_BLOCKS, 256, 0, stream>>>(hbuf, rowptr, col, nrm, dinv, hhi, hlo, N);
    k_gemm_mfma<<<gemmGrid, 256, 0, stream>>>(hhi, hlo, w1hi, w1lo, b1, hbuf, N, DH);
    // layer 2
    k_agg256<<<AGG_BLOCKS, 256, 0, stream>>>(hbuf, rowptr, col, nrm, dinv, hhi, hlo, N);
    k_gemm_mfma<<<gemmGrid, 256, 0, stream>>>(hhi, hlo, w2hi, w2lo, b2, hbuf, N, DH);

    dim3 poolGrid(64, POOL_S);
    k_pool1<<<poolGrid, 256, 0, stream>>>(hbuf, gstart, ppool);
    k_pool2<<<64, 256, 0, stream>>>(ppool, gstart, gpool);
    k_cls <<<64, 256, 0, stream>>>(gpool, Wc1, bc1, Wc2, bc2, out);
}

// Round 9
// 506.336 us; speedup vs baseline: 1.0568x; 1.0568x over previous
//
#include <hip/hip_runtime.h>

typedef short s16x8 __attribute__((ext_vector_type(8)));   // 8 bf16 = 4 VGPRs
typedef float fx4 __attribute__((ext_vector_type(4)));     // MFMA acc

#define AS_G(p) ((const __attribute__((address_space(1))) void*)(p))
#define AS_L(p) ((__attribute__((address_space(3))) void*)(p))

__device__ inline unsigned short f32_to_bf16(float f) {
    unsigned int u = __float_as_uint(f);
    return (unsigned short)((u + 0x7fffu + ((u >> 16) & 1u)) >> 16);
}
__device__ inline float bf16_to_f32(unsigned short b) {
    return __uint_as_float(((unsigned int)b) << 16);
}
__device__ inline void split2(float a, unsigned short& hi, unsigned short& lo) {
    hi = f32_to_bf16(a);
    lo = f32_to_bf16(a - bf16_to_f32(hi));
}

// ===================== graph preprocessing =====================

__global__ void k_deg(const int* __restrict__ dst, int E, int* __restrict__ deg) {
    int i = blockIdx.x * blockDim.x + threadIdx.x;
    if (i < E) atomicAdd(&deg[dst[i]], 1);
}

__global__ void k_dinv(const int* __restrict__ deg, int N, float* __restrict__ dinv) {
    int i = blockIdx.x * blockDim.x + threadIdx.x;
    if (i < N) dinv[i] = 1.0f / sqrtf((float)(deg[i] + 1));
}

__global__ void k_scan1(const int* __restrict__ deg, int N, int* __restrict__ part, int* __restrict__ bsum) {
    __shared__ int s[256];
    int i = blockIdx.x * 256 + threadIdx.x;
    int v = (i < N) ? deg[i] : 0;
    s[threadIdx.x] = v;
    __syncthreads();
    for (int off = 1; off < 256; off <<= 1) {
        int t = (threadIdx.x >= off) ? s[threadIdx.x - off] : 0;
        __syncthreads();
        s[threadIdx.x] += t;
        __syncthreads();
    }
    if (i < N) part[i] = s[threadIdx.x] - v;
    if (threadIdx.x == 255) bsum[blockIdx.x] = s[255];
}

__global__ void k_scan2(int* __restrict__ bsum, int nb) {
    __shared__ int s[256];
    int v = (threadIdx.x < nb) ? bsum[threadIdx.x] : 0;
    s[threadIdx.x] = v;
    __syncthreads();
    for (int off = 1; off < 256; off <<= 1) {
        int t = (threadIdx.x >= off) ? s[threadIdx.x - off] : 0;
        __syncthreads();
        s[threadIdx.x] += t;
        __syncthreads();
    }
    if (threadIdx.x < nb) bsum[threadIdx.x] = s[threadIdx.x] - v;
}

__global__ void k_scan3(const int* __restrict__ part, const int* __restrict__ bsum, int N, int E,
                        int* __restrict__ rowptr, int* __restrict__ cursor) {
    int i = blockIdx.x * 256 + threadIdx.x;
    if (i < N) {
        int v = part[i] + bsum[blockIdx.x];
        rowptr[i] = v;
        cursor[i] = v;
    }
    if (i == 0) rowptr[N] = E;
}

__global__ void k_fill(const int* __restrict__ src, const int* __restrict__ dst, int E,
                       const float* __restrict__ dinv, int* __restrict__ cursor,
                       int* __restrict__ col, float* __restrict__ nrm) {
    int e = blockIdx.x * blockDim.x + threadIdx.x;
    if (e < E) {
        int s = src[e], d = dst[e];
        int p = atomicAdd(&cursor[d], 1);
        col[p] = s;
        nrm[p] = dinv[s] * dinv[d];
    }
}

__global__ void k_gbounds(const int* __restrict__ batch, int N, int ngraphs, int* __restrict__ gstart) {
    int g = threadIdx.x;
    if (g > ngraphs) return;
    if (g == ngraphs) { gstart[g] = N; return; }
    int lo = 0, hi = N;
    while (lo < hi) {
        int mid = (lo + hi) >> 1;
        if (batch[mid] < g) lo = mid + 1; else hi = mid;
    }
    gstart[g] = lo;
}

// W [K][M] fp32 -> W^T split bf16 [M][K] (so B-fragments read contiguous k)
__global__ void k_split_wT(const float* __restrict__ W, int K, int M,
                           unsigned short* __restrict__ hiT, unsigned short* __restrict__ loT) {
    int i = blockIdx.x * 256 + threadIdx.x;
    if (i < K * M) {
        int k = i / M, n = i - k * M;
        unsigned short h, l;
        split2(W[i], h, l);
        hiT[(size_t)n * K + k] = h;
        loT[(size_t)n * K + k] = l;
    }
}

// ===================== split-bf16 MFMA GEMM + fused bias/ReLU =====================
// C[N x 256] = relu(A[N x K] @ B[K x 256] + bias), A split bf16, B pre-transposed split.
// C = Ahi*Bhi + Ahi*Blo + Alo*Bhi in fp32 acc (error ~2^-17 rel).
// Block 128x128, 4 waves 2x2, wave tile 64x64 = 4x4 mfma_f32_16x16x32_bf16.
// global_load_lds width=16; XOR bank-swizzle folded into per-lane global addresses.

__global__ __launch_bounds__(256) void k_gemm_mfma(
    const unsigned short* __restrict__ Ahi, const unsigned short* __restrict__ Alo,
    const unsigned short* __restrict__ BhiT, const unsigned short* __restrict__ BloT,
    const float* __restrict__ bias, float* __restrict__ C, int Nrows, int K) {
    __shared__ __align__(16) unsigned short sAhi[128 * 32];
    __shared__ __align__(16) unsigned short sAlo[128 * 32];
    __shared__ __align__(16) unsigned short sBhi[128 * 32];
    __shared__ __align__(16) unsigned short sBlo[128 * 32];

    const int tid = threadIdx.x;
    const int wid = tid >> 6, lane = tid & 63;
    const int row0 = blockIdx.y * 128;
    const int col0 = blockIdx.x * 128;
    const int wrow = wid & 1, wcol = wid >> 1;
    const int quad = lane >> 4, l16 = lane & 15;

    const unsigned short* garr = (wid == 0) ? Ahi : (wid == 1) ? Alo : (wid == 2) ? BhiT : BloT;
    unsigned short* sarr = (wid == 0) ? sAhi : (wid == 1) ? sAlo : (wid == 2) ? sBhi : sBlo;
    const bool isA = (wid < 2);

    const unsigned short* gp[8];
#pragma unroll
    for (int i = 0; i < 8; ++i) {
        int r = 16 * i + (lane >> 2);            // local row within 128-tile
        int s = lane & 3;                        // physical 16B slot in row
        int q = (s - (r >> 1)) & 3;              // logical k-chunk stored at this slot
        int grow = isA ? min(row0 + r, Nrows - 1) : (col0 + r);
        gp[i] = garr + (size_t)grow * K + q * 8;
    }

    int aidx[4], bidx[4];
#pragma unroll
    for (int t = 0; t < 4; ++t) {
        int ra = wrow * 64 + t * 16 + l16;
        aidx[t] = ra * 32 + ((quad + (ra >> 1)) & 3) * 8;
        int rb = wcol * 64 + t * 16 + l16;
        bidx[t] = rb * 32 + ((quad + (rb >> 1)) & 3) * 8;
    }

    fx4 acc[4][4] = {};

    for (int k0 = 0; k0 < K; k0 += 32) {
#pragma unroll
        for (int i = 0; i < 8; ++i)
            __builtin_amdgcn_global_load_lds(AS_G(gp[i] + k0), AS_L((char*)sarr + i * 1024), 16, 0, 0);
        __syncthreads();

        s16x8 ah[4], al[4];
#pragma unroll
        for (int mi = 0; mi < 4; ++mi) {
            ah[mi] = *(const s16x8*)&sAhi[aidx[mi]];
            al[mi] = *(const s16x8*)&sAlo[aidx[mi]];
        }
#pragma unroll
        for (int nj = 0; nj < 4; ++nj) {
            s16x8 bh = *(const s16x8*)&sBhi[bidx[nj]];
            s16x8 bl = *(const s16x8*)&sBlo[bidx[nj]];
#pragma unroll
            for (int mi = 0; mi < 4; ++mi) {
                acc[mi][nj] = __builtin_amdgcn_mfma_f32_16x16x32_bf16(ah[mi], bh, acc[mi][nj], 0, 0, 0);
                acc[mi][nj] = __builtin_amdgcn_mfma_f32_16x16x32_bf16(ah[mi], bl, acc[mi][nj], 0, 0, 0);
                acc[mi][nj] = __builtin_amdgcn_mfma_f32_16x16x32_bf16(al[mi], bh, acc[mi][nj], 0, 0, 0);
            }
        }
        __syncthreads();
    }

    // C/D layout: col = lane&15, row = quad*4 + reg  [m89-verified]
#pragma unroll
    for (int mi = 0; mi < 4; ++mi) {
        const int rbase = row0 + wrow * 64 + mi * 16 + quad * 4;
#pragma unroll
        for (int nj = 0; nj < 4; ++nj) {
            const int c = col0 + wcol * 64 + nj * 16 + l16;
            const float bc = bias[c];
#pragma unroll
            for (int reg = 0; reg < 4; ++reg) {
                int r = rbase + reg;
                if (r < Nrows) C[(size_t)r * 256 + c] = fmaxf(acc[mi][nj][reg] + bc, 0.f);
            }
        }
    }
}

// ===================== aggregation (pure  Â·H : selfnorm + weighted neighbor sum) ======
// WAVE-PER-NODE (reverted from persistent grid-stride: static node assignment forfeits
// the HW block scheduler's dynamic balancing and serializes node->node in a wave; it
// measured 94us vs 82us for this form). 8x edge unroll = 8 gathers in flight.

// D=128 (layer 0 on raw x): lane owns float2; output split-bf16.
__global__ __launch_bounds__(256) void k_agg128(const float* __restrict__ X, const int* __restrict__ rowptr,
                                                const int* __restrict__ col, const float* __restrict__ nrm,
                                                const float* __restrict__ dinv,
                                                unsigned short* __restrict__ outHi,
                                                unsigned short* __restrict__ outLo, int N) {
    const int wave = threadIdx.x >> 6, lane = threadIdx.x & 63;
    const int v = blockIdx.x * 4 + wave;
    if (v >= N) return;

    const float di = dinv[v];
    const float selfn = di * di;
    float2 h = ((const float2*)&X[(size_t)v * 128])[lane];
    float ax = selfn * h.x, ay = selfn * h.y;

    int e = rowptr[v];
    const int end = rowptr[v + 1];
    for (; e + 8 <= end; e += 8) {
        int u[8]; float w[8]; float2 g[8];
#pragma unroll
        for (int j = 0; j < 8; ++j) { u[j] = col[e + j]; w[j] = nrm[e + j]; }
#pragma unroll
        for (int j = 0; j < 8; ++j) g[j] = ((const float2*)&X[(size_t)u[j] * 128])[lane];
#pragma unroll
        for (int j = 0; j < 8; ++j) { ax += w[j] * g[j].x; ay += w[j] * g[j].y; }
    }
    for (; e < end; ++e) {
        const int u = col[e];
        const float w = nrm[e];
        float2 g = ((const float2*)&X[(size_t)u * 128])[lane];
        ax += w * g.x; ay += w * g.y;
    }

    ushort2 hi2, lo2;
    split2(ax, hi2.x, lo2.x);
    split2(ay, hi2.y, lo2.y);
    ((ushort2*)outHi)[(size_t)v * 64 + lane] = hi2;
    ((ushort2*)outLo)[(size_t)v * 64 + lane] = lo2;
}

// D=256 (layers 1,2 on fp32 H): lane owns float4; output split-bf16.
__global__ __launch_bounds__(256) void k_agg256(const float* __restrict__ H, const int* __restrict__ rowptr,
                                                const int* __restrict__ col, const float* __restrict__ nrm,
                                                const float* __restrict__ dinv,
                                                unsigned short* __restrict__ outHi,
                                                unsigned short* __restrict__ outLo, int N) {
    const int wave = threadIdx.x >> 6, lane = threadIdx.x & 63;
    const int v = blockIdx.x * 4 + wave;
    if (v >= N) return;

    const float di = dinv[v];
    const float selfn = di * di;
    float4 h = ((const float4*)&H[(size_t)v * 256])[lane];
    float ax = selfn * h.x, ay = selfn * h.y, az = selfn * h.z, aw = selfn * h.w;

    int e = rowptr[v];
    const int end = rowptr[v + 1];
    for (; e + 8 <= end; e += 8) {
        int u[8]; float w[8]; float4 g[8];
#pragma unroll
        for (int j = 0; j < 8; ++j) { u[j] = col[e + j]; w[j] = nrm[e + j]; }
#pragma unroll
        for (int j = 0; j < 8; ++j) g[j] = ((const float4*)&H[(size_t)u[j] * 256])[lane];
#pragma unroll
        for (int j = 0; j < 8; ++j) {
            ax += w[j] * g[j].x; ay += w[j] * g[j].y; az += w[j] * g[j].z; aw += w[j] * g[j].w;
        }
    }
    for (; e < end; ++e) {
        const int u = col[e];
        const float w = nrm[e];
        float4 g = ((const float4*)&H[(size_t)u * 256])[lane];
        ax += w * g.x; ay += w * g.y; az += w * g.z; aw += w * g.w;
    }

    ushort4 hi4, lo4;
    split2(ax, hi4.x, lo4.x);
    split2(ay, hi4.y, lo4.y);
    split2(az, hi4.z, lo4.z);
    split2(aw, hi4.w, lo4.w);
    ((ushort4*)outHi)[(size_t)v * 64 + lane] = hi4;
    ((ushort4*)outLo)[(size_t)v * 64 + lane] = lo4;
}

// ===================== mean pool, two-stage deterministic tree =====================
#define POOL_S 32

__global__ __launch_bounds__(256) void k_pool1(const float* __restrict__ H, const int* __restrict__ gstart,
                                               float* __restrict__ partial) {
    const int gid = blockIdx.x, slice = blockIdx.y, t = threadIdx.x;
    const int start = gstart[gid], end = gstart[gid + 1];
    const int len = end - start;
    const int chunk = (len + POOL_S - 1) / POOL_S;
    int a = start + slice * chunk;
    int b = a + chunk; if (b > end) b = end;
    float acc = 0.f;
    for (int n = a; n < b; ++n) acc += H[(size_t)n * 256 + t];
    partial[((size_t)gid * POOL_S + slice) * 256 + t] = acc;
}

__global__ __launch_bounds__(256) void k_pool2(const float* __restrict__ partial, const int* __restrict__ gstart,
                                               float* __restrict__ g) {
    const int gid = blockIdx.x, t = threadIdx.x;
    float acc = 0.f;
#pragma unroll
    for (int s = 0; s < POOL_S; ++s) acc += partial[((size_t)gid * POOL_S + s) * 256 + t];
    const float c = (float)(gstart[gid + 1] - gstart[gid]);
    g[gid * 256 + t] = acc / fmaxf(c, 1.0f);
}

// ===================== classifier head =====================

__global__ __launch_bounds__(256) void k_cls(const float* __restrict__ g, const float* __restrict__ Wc1,
                                             const float* __restrict__ bc1, const float* __restrict__ Wc2,
                                             const float* __restrict__ bc2, float* __restrict__ out) {
    __shared__ float sg[256], sh[256];
    const int b = blockIdx.x, t = threadIdx.x;
    sg[t] = g[b * 256 + t];
    __syncthreads();
    float acc = bc1[t];
    for (int k = 0; k < 256; ++k) acc += sg[k] * Wc1[k * 256 + t];
    sh[t] = fmaxf(acc, 0.f);
    __syncthreads();
    if (t < 5) {
        float o = bc2[t];
        for (int k = 0; k < 256; ++k) o += sh[k] * Wc2[k * 5 + t];
        out[b * 5 + t] = o;
    }
}

// ===================== launch =====================

extern "C" void kernel_launch(void* const* d_in, const int* in_sizes, int n_in,
                              void* d_out, int out_size, void* d_ws, size_t ws_size,
                              hipStream_t stream) {
    const float* x    = (const float*)d_in[0];
    const int*   eidx = (const int*)d_in[1];
    const int*   batch= (const int*)d_in[2];
    const float* W0 = (const float*)d_in[3];  const float* b0 = (const float*)d_in[4];
    const float* W1 = (const float*)d_in[5];  const float* b1 = (const float*)d_in[6];
    const float* W2 = (const float*)d_in[7];  const float* b2 = (const float*)d_in[8];
    const float* Wc1= (const float*)d_in[9];  const float* bc1= (const float*)d_in[10];
    const float* Wc2= (const float*)d_in[11]; const float* bc2= (const float*)d_in[12];
    float* out = (float*)d_out;

    const int N   = in_sizes[2];       // 50000
    const int E   = in_sizes[1] / 2;   // 500000
    const int DIN = in_sizes[0] / N;   // 128
    const int DH  = in_sizes[4];       // 256
    const int* src = eidx;
    const int* dst = eidx + E;

    char* p = (char*)d_ws;
    auto alloc = [&](size_t bytes) {
        char* r = p;
        p += (bytes + 255) & ~(size_t)255;
        return (void*)r;
    };
    float*          hbuf = (float*)alloc((size_t)N * DH * 4);           // gemm out (fp32), agg in, pool in
    unsigned short* hhi  = (unsigned short*)alloc((size_t)N * DH * 2);  // agg split out / gemm A in
    unsigned short* hlo  = (unsigned short*)alloc((size_t)N * DH * 2);
    unsigned short* w0hi = (unsigned short*)alloc((size_t)DH * DIN * 2);
    unsigned short* w0lo = (unsigned short*)alloc((size_t)DH * DIN * 2);
    unsigned short* w1hi = (unsigned short*)alloc((size_t)DH * DH * 2);
    unsigned short* w1lo = (unsigned short*)alloc((size_t)DH * DH * 2);
    unsigned short* w2hi = (unsigned short*)alloc((size_t)DH * DH * 2);
    unsigned short* w2lo = (unsigned short*)alloc((size_t)DH * DH * 2);
    int*   deg   = (int*)alloc((size_t)N * 4);
    float* dinv  = (float*)alloc((size_t)N * 4);
    int*   part  = (int*)alloc((size_t)N * 4);
    int*   bsum  = (int*)alloc(256 * 4);
    int*   rowptr= (int*)alloc((size_t)(N + 1) * 4);
    int*   cursor= (int*)alloc((size_t)N * 4);
    int*   col   = (int*)alloc((size_t)E * 4);
    float* nrm   = (float*)alloc((size_t)E * 4);
    int*   gstart= (int*)alloc(65 * 4);
    float* ppool = (float*)alloc(64 * (size_t)POOL_S * DH * 4);
    float* gpool = (float*)alloc(64 * (size_t)DH * 4);

    hipMemsetAsync(deg, 0, (size_t)N * 4, stream);

    const int nb = (N + 255) / 256;
    k_deg <<<(E + 255) / 256, 256, 0, stream>>>(dst, E, deg);
    k_dinv<<<nb, 256, 0, stream>>>(deg, N, dinv);
    k_scan1<<<nb, 256, 0, stream>>>(deg, N, part, bsum);
    k_scan2<<<1, 256, 0, stream>>>(bsum, nb);
    k_scan3<<<nb, 256, 0, stream>>>(part, bsum, N, E, rowptr, cursor);
    k_fill<<<(E + 255) / 256, 256, 0, stream>>>(src, dst, E, dinv, cursor, col, nrm);
    k_gbounds<<<1, 128, 0, stream>>>(batch, N, 64, gstart);

    k_split_wT<<<(DIN * DH + 255) / 256, 256, 0, stream>>>(W0, DIN, DH, w0hi, w0lo);
    k_split_wT<<<(DH * DH + 255) / 256, 256, 0, stream>>>(W1, DH, DH, w1hi, w1lo);
    k_split_wT<<<(DH * DH + 255) / 256, 256, 0, stream>>>(W2, DH, DH, w2hi, w2lo);

    dim3 gemmGrid(DH / 128, (N + 127) / 128);
    const int aggBlocks = (N + 3) / 4;

    // layer 0: agg(x) [128-d, half gather traffic] -> gemm(relu(.W0+b0))
    k_agg128<<<aggBlocks, 256, 0, stream>>>(x, rowptr, col, nrm, dinv, hhi, hlo, N);
    k_gemm_mfma<<<gemmGrid, 256, 0, stream>>>(hhi, hlo, w0hi, w0lo, b0, hbuf, N, DIN);
    // layer 1
    k_agg256<<<aggBlocks, 256, 0, stream>>>(hbuf, rowptr, col, nrm, dinv, hhi, hlo, N);
    k_gemm_mfma<<<gemmGrid, 256, 0, stream>>>(hhi, hlo, w1hi, w1lo, b1, hbuf, N, DH);
    // layer 2
    k_agg256<<<aggBlocks, 256, 0, stream>>>(hbuf, rowptr, col, nrm, dinv, hhi, hlo, N);
    k_gemm_mfma<<<gemmGrid, 256, 0, stream>>>(hhi, hlo, w2hi, w2lo, b2, hbuf, N, DH);

    dim3 poolGrid(64, POOL_S);
    k_pool1<<<poolGrid, 256, 0, stream>>>(hbuf, gstart, ppool);
    k_pool2<<<64, 256, 0, stream>>>(ppool, gstart, gpool);
    k_cls <<<64, 256, 0, stream>>>(gpool, Wc1, bc1, Wc2, bc2, out);
}

// Round 10
// 478.955 us; speedup vs baseline: 1.1173x; 1.0572x over previous
//
#include <hip/hip_runtime.h>

typedef short s16x8 __attribute__((ext_vector_type(8)));   // 8 bf16 = 4 VGPRs
typedef float fx4 __attribute__((ext_vector_type(4)));     // MFMA acc

#define AS_G(p) ((const __attribute__((address_space(1))) void*)(p))
#define AS_L(p) ((__attribute__((address_space(3))) void*)(p))

__device__ inline unsigned short f32_to_bf16(float f) {
    unsigned int u = __float_as_uint(f);
    return (unsigned short)((u + 0x7fffu + ((u >> 16) & 1u)) >> 16);
}
__device__ inline float bf16_to_f32(unsigned short b) {
    return __uint_as_float(((unsigned int)b) << 16);
}
__device__ inline void split2(float a, unsigned short& hi, unsigned short& lo) {
    hi = f32_to_bf16(a);
    lo = f32_to_bf16(a - bf16_to_f32(hi));
}

// ===================== graph preprocessing =====================

__global__ void k_deg(const int* __restrict__ dst, int E, int* __restrict__ deg) {
    int i = blockIdx.x * blockDim.x + threadIdx.x;
    if (i < E) atomicAdd(&deg[dst[i]], 1);
}

// fused: block-local exclusive scan of deg  +  dinv computation
__global__ void k_scan1(const int* __restrict__ deg, int N, int* __restrict__ part, int* __restrict__ bsum,
                        float* __restrict__ dinv) {
    __shared__ int s[256];
    int i = blockIdx.x * 256 + threadIdx.x;
    int v = (i < N) ? deg[i] : 0;
    if (i < N) dinv[i] = 1.0f / sqrtf((float)(v + 1));  // +1 self-loop
    s[threadIdx.x] = v;
    __syncthreads();
    for (int off = 1; off < 256; off <<= 1) {
        int t = (threadIdx.x >= off) ? s[threadIdx.x - off] : 0;
        __syncthreads();
        s[threadIdx.x] += t;
        __syncthreads();
    }
    if (i < N) part[i] = s[threadIdx.x] - v;
    if (threadIdx.x == 255) bsum[blockIdx.x] = s[255];
}

// fused: scan of block sums  +  graph-boundary binary search over sorted batch
__global__ void k_scan2(int* __restrict__ bsum, int nb,
                        const int* __restrict__ batch, int N, int ngraphs, int* __restrict__ gstart) {
    // gbounds part (independent of scan)
    int g = threadIdx.x;
    if (g <= ngraphs) {
        if (g == ngraphs) gstart[g] = N;
        else {
            int lo = 0, hi = N;
            while (lo < hi) {
                int mid = (lo + hi) >> 1;
                if (batch[mid] < g) lo = mid + 1; else hi = mid;
            }
            gstart[g] = lo;
        }
    }
    __shared__ int s[256];
    int v = (threadIdx.x < nb) ? bsum[threadIdx.x] : 0;
    s[threadIdx.x] = v;
    __syncthreads();
    for (int off = 1; off < 256; off <<= 1) {
        int t = (threadIdx.x >= off) ? s[threadIdx.x - off] : 0;
        __syncthreads();
        s[threadIdx.x] += t;
        __syncthreads();
    }
    if (threadIdx.x < nb) bsum[threadIdx.x] = s[threadIdx.x] - v;
}

__global__ void k_scan3(const int* __restrict__ part, const int* __restrict__ bsum, int N, int E,
                        int* __restrict__ rowptr, int* __restrict__ cursor) {
    int i = blockIdx.x * 256 + threadIdx.x;
    if (i < N) {
        int v = part[i] + bsum[blockIdx.x];
        rowptr[i] = v;
        cursor[i] = v;
    }
    if (i == 0) rowptr[N] = E;
}

__global__ void k_fill(const int* __restrict__ src, const int* __restrict__ dst, int E,
                       const float* __restrict__ dinv, int* __restrict__ cursor,
                       int* __restrict__ col, float* __restrict__ nrm) {
    int e = blockIdx.x * blockDim.x + threadIdx.x;
    if (e < E) {
        int s = src[e], d = dst[e];
        int p = atomicAdd(&cursor[d], 1);
        col[p] = s;
        nrm[p] = dinv[s] * dinv[d];
    }
}

// all three weights split+transposed in one dispatch.
// W [K][M] fp32 -> W^T split bf16 [M][K].
__global__ void k_split_w3(const float* __restrict__ W0, unsigned short* __restrict__ h0, unsigned short* __restrict__ l0,
                           const float* __restrict__ W1, unsigned short* __restrict__ h1, unsigned short* __restrict__ l1,
                           const float* __restrict__ W2, unsigned short* __restrict__ h2, unsigned short* __restrict__ l2,
                           int DIN, int DH) {
    int i = blockIdx.x * 256 + threadIdx.x;
    const int n0 = DIN * DH, n1 = DH * DH;
    const float* W; unsigned short *hT, *lT; int K, li;
    if (i < n0) { W = W0; hT = h0; lT = l0; K = DIN; li = i; }
    else if (i < n0 + n1) { W = W1; hT = h1; lT = l1; K = DH; li = i - n0; }
    else if (i < n0 + 2 * n1) { W = W2; hT = h2; lT = l2; K = DH; li = i - n0 - n1; }
    else return;
    int k = li / DH, n = li - k * DH;
    unsigned short h, l;
    split2(W[li], h, l);
    hT[(size_t)n * K + k] = h;
    lT[(size_t)n * K + k] = l;
}

// ===================== split-bf16 MFMA GEMM + fused bias/ReLU =====================
// C[N x 256] = relu(A[N x K] @ B[K x 256] + bias), A split bf16, B pre-transposed split.
// C = Ahi*Bhi + Ahi*Blo + Alo*Bhi in fp32 acc (error ~2^-17 rel).

__global__ __launch_bounds__(256) void k_gemm_mfma(
    const unsigned short* __restrict__ Ahi, const unsigned short* __restrict__ Alo,
    const unsigned short* __restrict__ BhiT, const unsigned short* __restrict__ BloT,
    const float* __restrict__ bias, float* __restrict__ C, int Nrows, int K) {
    __shared__ __align__(16) unsigned short sAhi[128 * 32];
    __shared__ __align__(16) unsigned short sAlo[128 * 32];
    __shared__ __align__(16) unsigned short sBhi[128 * 32];
    __shared__ __align__(16) unsigned short sBlo[128 * 32];

    const int tid = threadIdx.x;
    const int wid = tid >> 6, lane = tid & 63;
    const int row0 = blockIdx.y * 128;
    const int col0 = blockIdx.x * 128;
    const int wrow = wid & 1, wcol = wid >> 1;
    const int quad = lane >> 4, l16 = lane & 15;

    const unsigned short* garr = (wid == 0) ? Ahi : (wid == 1) ? Alo : (wid == 2) ? BhiT : BloT;
    unsigned short* sarr = (wid == 0) ? sAhi : (wid == 1) ? sAlo : (wid == 2) ? sBhi : sBlo;
    const bool isA = (wid < 2);

    const unsigned short* gp[8];
#pragma unroll
    for (int i = 0; i < 8; ++i) {
        int r = 16 * i + (lane >> 2);
        int s = lane & 3;
        int q = (s - (r >> 1)) & 3;              // XOR bank-swizzle in global address
        int grow = isA ? min(row0 + r, Nrows - 1) : (col0 + r);
        gp[i] = garr + (size_t)grow * K + q * 8;
    }

    int aidx[4], bidx[4];
#pragma unroll
    for (int t = 0; t < 4; ++t) {
        int ra = wrow * 64 + t * 16 + l16;
        aidx[t] = ra * 32 + ((quad + (ra >> 1)) & 3) * 8;
        int rb = wcol * 64 + t * 16 + l16;
        bidx[t] = rb * 32 + ((quad + (rb >> 1)) & 3) * 8;
    }

    fx4 acc[4][4] = {};

    for (int k0 = 0; k0 < K; k0 += 32) {
#pragma unroll
        for (int i = 0; i < 8; ++i)
            __builtin_amdgcn_global_load_lds(AS_G(gp[i] + k0), AS_L((char*)sarr + i * 1024), 16, 0, 0);
        __syncthreads();

        s16x8 ah[4], al[4];
#pragma unroll
        for (int mi = 0; mi < 4; ++mi) {
            ah[mi] = *(const s16x8*)&sAhi[aidx[mi]];
            al[mi] = *(const s16x8*)&sAlo[aidx[mi]];
        }
#pragma unroll
        for (int nj = 0; nj < 4; ++nj) {
            s16x8 bh = *(const s16x8*)&sBhi[bidx[nj]];
            s16x8 bl = *(const s16x8*)&sBlo[bidx[nj]];
#pragma unroll
            for (int mi = 0; mi < 4; ++mi) {
                acc[mi][nj] = __builtin_amdgcn_mfma_f32_16x16x32_bf16(ah[mi], bh, acc[mi][nj], 0, 0, 0);
                acc[mi][nj] = __builtin_amdgcn_mfma_f32_16x16x32_bf16(ah[mi], bl, acc[mi][nj], 0, 0, 0);
                acc[mi][nj] = __builtin_amdgcn_mfma_f32_16x16x32_bf16(al[mi], bh, acc[mi][nj], 0, 0, 0);
            }
        }
        __syncthreads();
    }

    // C/D layout: col = lane&15, row = quad*4 + reg  [m89-verified]
#pragma unroll
    for (int mi = 0; mi < 4; ++mi) {
        const int rbase = row0 + wrow * 64 + mi * 16 + quad * 4;
#pragma unroll
        for (int nj = 0; nj < 4; ++nj) {
            const int c = col0 + wcol * 64 + nj * 16 + l16;
            const float bc = bias[c];
#pragma unroll
            for (int reg = 0; reg < 4; ++reg) {
                int r = rbase + reg;
                if (r < Nrows) C[(size_t)r * 256 + c] = fmaxf(acc[mi][nj][reg] + bc, 0.f);
            }
        }
    }
}

// Layer-2 variant: instead of writing C, accumulate relu(acc+bias) per-graph into
// gsum[64][256] (mean-pool numerator). Per-wave in-register segment reduction over
// its 64 rows (batch sorted => <=2-3 segments per 128-row tile), cross-quad shfl_xor,
// then one atomicAdd instruction (16 lanes, contiguous) per (nj, graph) per wave.
__global__ __launch_bounds__(256) void k_gemm_pool(
    const unsigned short* __restrict__ Ahi, const unsigned short* __restrict__ Alo,
    const unsigned short* __restrict__ BhiT, const unsigned short* __restrict__ BloT,
    const float* __restrict__ bias, const int* __restrict__ batch,
    float* __restrict__ gsum, int Nrows, int K) {
    __shared__ __align__(16) unsigned short sAhi[128 * 32];
    __shared__ __align__(16) unsigned short sAlo[128 * 32];
    __shared__ __align__(16) unsigned short sBhi[128 * 32];
    __shared__ __align__(16) unsigned short sBlo[128 * 32];

    const int tid = threadIdx.x;
    const int wid = tid >> 6, lane = tid & 63;
    const int row0 = blockIdx.y * 128;
    const int col0 = blockIdx.x * 128;
    const int wrow = wid & 1, wcol = wid >> 1;
    const int quad = lane >> 4, l16 = lane & 15;

    const unsigned short* garr = (wid == 0) ? Ahi : (wid == 1) ? Alo : (wid == 2) ? BhiT : BloT;
    unsigned short* sarr = (wid == 0) ? sAhi : (wid == 1) ? sAlo : (wid == 2) ? sBhi : sBlo;
    const bool isA = (wid < 2);

    const unsigned short* gp[8];
#pragma unroll
    for (int i = 0; i < 8; ++i) {
        int r = 16 * i + (lane >> 2);
        int s = lane & 3;
        int q = (s - (r >> 1)) & 3;
        int grow = isA ? min(row0 + r, Nrows - 1) : (col0 + r);
        gp[i] = garr + (size_t)grow * K + q * 8;
    }

    int aidx[4], bidx[4];
#pragma unroll
    for (int t = 0; t < 4; ++t) {
        int ra = wrow * 64 + t * 16 + l16;
        aidx[t] = ra * 32 + ((quad + (ra >> 1)) & 3) * 8;
        int rb = wcol * 64 + t * 16 + l16;
        bidx[t] = rb * 32 + ((quad + (rb >> 1)) & 3) * 8;
    }

    fx4 acc[4][4] = {};

    for (int k0 = 0; k0 < K; k0 += 32) {
#pragma unroll
        for (int i = 0; i < 8; ++i)
            __builtin_amdgcn_global_load_lds(AS_G(gp[i] + k0), AS_L((char*)sarr + i * 1024), 16, 0, 0);
        __syncthreads();

        s16x8 ah[4], al[4];
#pragma unroll
        for (int mi = 0; mi < 4; ++mi) {
            ah[mi] = *(const s16x8*)&sAhi[aidx[mi]];
            al[mi] = *(const s16x8*)&sAlo[aidx[mi]];
        }
#pragma unroll
        for (int nj = 0; nj < 4; ++nj) {
            s16x8 bh = *(const s16x8*)&sBhi[bidx[nj]];
            s16x8 bl = *(const s16x8*)&sBlo[bidx[nj]];
#pragma unroll
            for (int mi = 0; mi < 4; ++mi) {
                acc[mi][nj] = __builtin_amdgcn_mfma_f32_16x16x32_bf16(ah[mi], bh, acc[mi][nj], 0, 0, 0);
                acc[mi][nj] = __builtin_amdgcn_mfma_f32_16x16x32_bf16(ah[mi], bl, acc[mi][nj], 0, 0, 0);
                acc[mi][nj] = __builtin_amdgcn_mfma_f32_16x16x32_bf16(al[mi], bh, acc[mi][nj], 0, 0, 0);
            }
        }
        __syncthreads();
    }

    // pooling epilogue
    int bg[4][4];  // graph id of each (mi, reg) row this lane owns; -1 if padded
#pragma unroll
    for (int mi = 0; mi < 4; ++mi)
#pragma unroll
        for (int reg = 0; reg < 4; ++reg) {
            int r = row0 + wrow * 64 + mi * 16 + quad * 4 + reg;
            bg[mi][reg] = (r < Nrows) ? batch[r] : -1;
        }
    const int gfirst = batch[row0 < Nrows ? row0 : (Nrows - 1)];
    const int glast  = batch[min(row0 + 127, Nrows - 1)];

#pragma unroll
    for (int nj = 0; nj < 4; ++nj) {
        const int c = col0 + wcol * 64 + nj * 16 + l16;
        const float bc = bias[c];
        for (int g = gfirst; g <= glast; ++g) {
            float s = 0.f;
#pragma unroll
            for (int mi = 0; mi < 4; ++mi)
#pragma unroll
                for (int reg = 0; reg < 4; ++reg)
                    if (bg[mi][reg] == g) s += fmaxf(acc[mi][nj][reg] + bc, 0.f);
            s += __shfl_xor(s, 16);
            s += __shfl_xor(s, 32);
            if (quad == 0) atomicAdd(&gsum[g * 256 + c], s);
        }
    }
}

// ===================== aggregation (pure  Â·H : selfnorm + weighted neighbor sum) ======
// WAVE-PER-NODE family (HW block scheduler gives dynamic balancing; persistent
// grid-stride measured 94us vs 82us). 8 gathers in flight per wave.

// D=128 (layer 0 on raw x): HALF-WAVE per node, lane owns float4 (32 lanes x 16B = 512B row).
// 2 nodes/wave, unroll 4 => 8 outstanding 512B gathers per wave.
__global__ __launch_bounds__(256) void k_agg128(const float* __restrict__ X, const int* __restrict__ rowptr,
                                                const int* __restrict__ col, const float* __restrict__ nrm,
                                                const float* __restrict__ dinv,
                                                unsigned short* __restrict__ outHi,
                                                unsigned short* __restrict__ outLo, int N) {
    const int half = threadIdx.x >> 5, sub = threadIdx.x & 31;   // half-wave id in block [0,8)
    const int v = blockIdx.x * 8 + half;
    if (v >= N) return;

    const float di = dinv[v];
    const float selfn = di * di;
    float4 h = ((const float4*)&X[(size_t)v * 128])[sub];
    float ax = selfn * h.x, ay = selfn * h.y, az = selfn * h.z, aw = selfn * h.w;

    int e = rowptr[v];
    const int end = rowptr[v + 1];
    for (; e + 4 <= end; e += 4) {
        int u[4]; float w[4]; float4 g[4];
#pragma unroll
        for (int j = 0; j < 4; ++j) { u[j] = col[e + j]; w[j] = nrm[e + j]; }
#pragma unroll
        for (int j = 0; j < 4; ++j) g[j] = ((const float4*)&X[(size_t)u[j] * 128])[sub];
#pragma unroll
        for (int j = 0; j < 4; ++j) {
            ax += w[j] * g[j].x; ay += w[j] * g[j].y; az += w[j] * g[j].z; aw += w[j] * g[j].w;
        }
    }
    for (; e < end; ++e) {
        const int u = col[e];
        const float w = nrm[e];
        float4 g = ((const float4*)&X[(size_t)u * 128])[sub];
        ax += w * g.x; ay += w * g.y; az += w * g.z; aw += w * g.w;
    }

    ushort4 hi4, lo4;
    split2(ax, hi4.x, lo4.x);
    split2(ay, hi4.y, lo4.y);
    split2(az, hi4.z, lo4.z);
    split2(aw, hi4.w, lo4.w);
    ((ushort4*)outHi)[(size_t)v * 32 + sub] = hi4;
    ((ushort4*)outLo)[(size_t)v * 32 + sub] = lo4;
}

// D=256 (layers 1,2 on fp32 H): wave per node, lane owns float4; output split-bf16.
__global__ __launch_bounds__(256) void k_agg256(const float* __restrict__ H, const int* __restrict__ rowptr,
                                                const int* __restrict__ col, const float* __restrict__ nrm,
                                                const float* __restrict__ dinv,
                                                unsigned short* __restrict__ outHi,
                                                unsigned short* __restrict__ outLo, int N) {
    const int wave = threadIdx.x >> 6, lane = threadIdx.x & 63;
    const int v = blockIdx.x * 4 + wave;
    if (v >= N) return;

    const float di = dinv[v];
    const float selfn = di * di;
    float4 h = ((const float4*)&H[(size_t)v * 256])[lane];
    float ax = selfn * h.x, ay = selfn * h.y, az = selfn * h.z, aw = selfn * h.w;

    int e = rowptr[v];
    const int end = rowptr[v + 1];
    for (; e + 8 <= end; e += 8) {
        int u[8]; float w[8]; float4 g[8];
#pragma unroll
        for (int j = 0; j < 8; ++j) { u[j] = col[e + j]; w[j] = nrm[e + j]; }
#pragma unroll
        for (int j = 0; j < 8; ++j) g[j] = ((const float4*)&H[(size_t)u[j] * 256])[lane];
#pragma unroll
        for (int j = 0; j < 8; ++j) {
            ax += w[j] * g[j].x; ay += w[j] * g[j].y; az += w[j] * g[j].z; aw += w[j] * g[j].w;
        }
    }
    for (; e < end; ++e) {
        const int u = col[e];
        const float w = nrm[e];
        float4 g = ((const float4*)&H[(size_t)u * 256])[lane];
        ax += w * g.x; ay += w * g.y; az += w * g.z; aw += w * g.w;
    }

    ushort4 hi4, lo4;
    split2(ax, hi4.x, lo4.x);
    split2(ay, hi4.y, lo4.y);
    split2(az, hi4.z, lo4.z);
    split2(aw, hi4.w, lo4.w);
    ((ushort4*)outHi)[(size_t)v * 64 + lane] = hi4;
    ((ushort4*)outLo)[(size_t)v * 64 + lane] = lo4;
}

// ===================== fused mean-pool finalize + classifier head =====================

__global__ __launch_bounds__(256) void k_poolcls(const float* __restrict__ gsum, const int* __restrict__ gstart,
                                                 const float* __restrict__ Wc1, const float* __restrict__ bc1,
                                                 const float* __restrict__ Wc2, const float* __restrict__ bc2,
                                                 float* __restrict__ out) {
    __shared__ float sg[256], sh[256];
    const int b = blockIdx.x, t = threadIdx.x;
    const float c = (float)(gstart[b + 1] - gstart[b]);
    sg[t] = gsum[b * 256 + t] / fmaxf(c, 1.0f);
    __syncthreads();
    float acc = bc1[t];
    for (int k = 0; k < 256; ++k) acc += sg[k] * Wc1[k * 256 + t];
    sh[t] = fmaxf(acc, 0.f);
    __syncthreads();
    if (t < 5) {
        float o = bc2[t];
        for (int k = 0; k < 256; ++k) o += sh[k] * Wc2[k * 5 + t];
        out[b * 5 + t] = o;
    }
}

// ===================== launch =====================

extern "C" void kernel_launch(void* const* d_in, const int* in_sizes, int n_in,
                              void* d_out, int out_size, void* d_ws, size_t ws_size,
                              hipStream_t stream) {
    const float* x    = (const float*)d_in[0];
    const int*   eidx = (const int*)d_in[1];
    const int*   batch= (const int*)d_in[2];
    const float* W0 = (const float*)d_in[3];  const float* b0 = (const float*)d_in[4];
    const float* W1 = (const float*)d_in[5];  const float* b1 = (const float*)d_in[6];
    const float* W2 = (const float*)d_in[7];  const float* b2 = (const float*)d_in[8];
    const float* Wc1= (const float*)d_in[9];  const float* bc1= (const float*)d_in[10];
    const float* Wc2= (const float*)d_in[11]; const float* bc2= (const float*)d_in[12];
    float* out = (float*)d_out;

    const int N   = in_sizes[2];       // 50000
    const int E   = in_sizes[1] / 2;   // 500000
    const int DIN = in_sizes[0] / N;   // 128
    const int DH  = in_sizes[4];       // 256
    const int* src = eidx;
    const int* dst = eidx + E;

    char* p = (char*)d_ws;
    auto alloc = [&](size_t bytes) {
        char* r = p;
        p += (bytes + 255) & ~(size_t)255;
        return (void*)r;
    };
    float*          hbuf = (float*)alloc((size_t)N * DH * 4);           // gemm0/1 out (fp32), agg in
    unsigned short* hhi  = (unsigned short*)alloc((size_t)N * DH * 2);  // agg split out / gemm A in
    unsigned short* hlo  = (unsigned short*)alloc((size_t)N * DH * 2);
    unsigned short* w0hi = (unsigned short*)alloc((size_t)DH * DIN * 2);
    unsigned short* w0lo = (unsigned short*)alloc((size_t)DH * DIN * 2);
    unsigned short* w1hi = (unsigned short*)alloc((size_t)DH * DH * 2);
    unsigned short* w1lo = (unsigned short*)alloc((size_t)DH * DH * 2);
    unsigned short* w2hi = (unsigned short*)alloc((size_t)DH * DH * 2);
    unsigned short* w2lo = (unsigned short*)alloc((size_t)DH * DH * 2);
    int*   deg   = (int*)alloc((size_t)N * 4);
    float* gsum  = (float*)alloc(64 * (size_t)DH * 4);   // adjacent to deg: one memset covers both
    float* dinv  = (float*)alloc((size_t)N * 4);
    int*   part  = (int*)alloc((size_t)N * 4);
    int*   bsum  = (int*)alloc(256 * 4);
    int*   rowptr= (int*)alloc((size_t)(N + 1) * 4);
    int*   cursor= (int*)alloc((size_t)N * 4);
    int*   col   = (int*)alloc((size_t)E * 4);
    float* nrm   = (float*)alloc((size_t)E * 4);
    int*   gstart= (int*)alloc(65 * 4);

    // one memset: deg (padded) + gsum are contiguous
    hipMemsetAsync(deg, 0, (size_t)((char*)gsum - (char*)deg) + 64 * (size_t)DH * 4, stream);

    const int nb = (N + 255) / 256;
    k_deg  <<<(E + 255) / 256, 256, 0, stream>>>(dst, E, deg);
    k_scan1<<<nb, 256, 0, stream>>>(deg, N, part, bsum, dinv);
    k_scan2<<<1, 256, 0, stream>>>(bsum, nb, batch, N, 64, gstart);
    k_scan3<<<nb, 256, 0, stream>>>(part, bsum, N, E, rowptr, cursor);
    k_fill <<<(E + 255) / 256, 256, 0, stream>>>(src, dst, E, dinv, cursor, col, nrm);

    const int wtot = DIN * DH + 2 * DH * DH;
    k_split_w3<<<(wtot + 255) / 256, 256, 0, stream>>>(W0, w0hi, w0lo, W1, w1hi, w1lo, W2, w2hi, w2lo, DIN, DH);

    dim3 gemmGrid(DH / 128, (N + 127) / 128);

    // layer 0: agg(x) [128-d, half gather traffic] -> gemm(relu(.W0+b0))
    k_agg128<<<(N + 7) / 8, 256, 0, stream>>>(x, rowptr, col, nrm, dinv, hhi, hlo, N);
    k_gemm_mfma<<<gemmGrid, 256, 0, stream>>>(hhi, hlo, w0hi, w0lo, b0, hbuf, N, DIN);
    // layer 1
    k_agg256<<<(N + 3) / 4, 256, 0, stream>>>(hbuf, rowptr, col, nrm, dinv, hhi, hlo, N);
    k_gemm_mfma<<<gemmGrid, 256, 0, stream>>>(hhi, hlo, w1hi, w1lo, b1, hbuf, N, DH);
    // layer 2: gemm with fused per-graph pooling epilogue (no N x 256 write, no pool pass)
    k_agg256<<<(N + 3) / 4, 256, 0, stream>>>(hbuf, rowptr, col, nrm, dinv, hhi, hlo, N);
    k_gemm_pool<<<gemmGrid, 256, 0, stream>>>(hhi, hlo, w2hi, w2lo, b2, batch, gsum, N, DH);

    k_poolcls<<<64, 256, 0, stream>>>(gsum, gstart, Wc1, bc1, Wc2, bc2, out);
}